// Round 7
// baseline (607.239 us; speedup 1.0000x reference)
//
#include <hip/hip_runtime.h>
#include <hip/hip_bf16.h>
#include <cmath>

// Problem constants (B=8, H=W=112, C=192, heads=8, hd=24, ps=7, hid=768)
#define C_DIM 192
#define HID 768

typedef __attribute__((ext_vector_type(8))) __bf16 bf16x8;
typedef __attribute__((ext_vector_type(4))) float f32x4;
typedef __attribute__((ext_vector_type(2))) float f32x2;
typedef __attribute__((ext_vector_type(8))) unsigned short u16x8;
typedef __attribute__((ext_vector_type(4))) unsigned int u32x4;

__device__ __forceinline__ void gload_lds16(const void* g, void* l) {
  __builtin_amdgcn_global_load_lds(
      (__attribute__((address_space(1))) void*)(const_cast<void*>(g)),
      (__attribute__((address_space(3))) void*)(l), 16, 0, 0);
}

__device__ __forceinline__ float bfu2f(ushort u) {
  return __uint_as_float((unsigned)u << 16);
}
__device__ __forceinline__ ushort f2bfu(float f) {
  __hip_bfloat16 h = __float2bfloat16(f);
  return *reinterpret_cast<ushort*>(&h);
}
// tanh-form GELU, exp2-folded + raw v_rcp (validated R6, absmax 0.0156)
__device__ __forceinline__ float fgelu(float x) {
  float z = x * (2.30226545f + 0.10293942f * x * x);  // (1.59577,0.0713548)*log2e
  float e = __builtin_amdgcn_exp2f(-z);
  return x * __builtin_amdgcn_rcpf(1.f + e);
}

// ---------------- prep: weights fp32 -> bf16 (+ fold q scale) ----------------
__global__ __launch_bounds__(256) void prep_kernel(
    const float* __restrict__ q_w, const float* __restrict__ q_b,
    const float* __restrict__ kv_w, const float* __restrict__ kv_b,
    const float* __restrict__ proj_w, const float* __restrict__ fc1_w,
    const float* __restrict__ fc2_w,
    __hip_bfloat16* __restrict__ wcat, float* __restrict__ bcat,
    __hip_bfloat16* __restrict__ projw, __hip_bfloat16* __restrict__ fc1w,
    __hip_bfloat16* __restrict__ fc2w)
{
  int idx = blockIdx.x * 256 + threadIdx.x;
  const float scale = 0.20412414523193154f;  // 24^-0.5
  if (idx < 110592) {
    float v = (idx < 36864) ? q_w[idx] * scale : kv_w[idx - 36864];
    wcat[idx] = __float2bfloat16(v);
  }
  if (idx < 576) bcat[idx] = (idx < 192) ? q_b[idx] * scale : kv_b[idx - 192];
  if (idx < 36864) projw[idx] = __float2bfloat16(proj_w[idx]);
  if (idx < 147456) {
    fc1w[idx] = __float2bfloat16(fc1_w[idx]);
    fc2w[idx] = __float2bfloat16(fc2_w[idx]);
  }
}

// ===== GEMM variant A: K=192, A-tile LDS-resident, serial n-tiles ===========
template <int EPI>
__global__ __launch_bounds__(512, 4) void gemmA_kernel(
    const ushort* __restrict__ X, int lda, const ushort* __restrict__ W,
    const float* __restrict__ bias, const float* __restrict__ addin,
    void* __restrict__ outp, int N)
{
  __shared__ __align__(16) ushort Al[128 * 192];  // 49152 B
  __shared__ __align__(16) ushort Bl[64 * 192];   // 24576 B
  const int tid = threadIdx.x;
  const int wv = tid >> 6;          // 0..7
  const int lane = tid & 63;
  const int quad = lane >> 4;
  const int m15 = lane & 15;
  const long mBase = (long)blockIdx.y * 128;
  const int NT = N >> 6;

  #pragma unroll
  for (int r = 0; r < 6; ++r) {
    int sI = tid + r * 512;
    int row = sI / 24;
    int cs = sI - row * 24;
    int gc = cs - (row % 24); if (gc < 0) gc += 24;
    gload_lds16(X + (mBase + row) * (long)lda + gc * 8, Al + sI * 8);
  }

  const int rA0 = wv * 16 + m15;
  const int rA0m = rA0 % 24;

  for (int nt = 0; nt < NT; ++nt) {
    __syncthreads();
    #pragma unroll
    for (int r = 0; r < 3; ++r) {
      int sI = tid + r * 512;
      int row = sI / 24;
      int cs = sI - row * 24;
      int gc = cs - (row % 24); if (gc < 0) gc += 24;
      gload_lds16(W + (long)(nt * 64 + row) * 192 + gc * 8, Bl + sI * 8);
    }
    __syncthreads();

    f32x4 acc[4];
    #pragma unroll
    for (int c = 0; c < 4; ++c) acc[c] = (f32x4){0.f, 0.f, 0.f, 0.f};

    #pragma unroll
    for (int ks = 0; ks < 6; ++ks) {
      const int l = ks * 4 + quad;
      int pa0 = l + rA0m; if (pa0 >= 24) pa0 -= 24;
      bf16x8 a0 = *(const bf16x8*)&Al[rA0 * 192 + pa0 * 8];
      #pragma unroll
      for (int ct = 0; ct < 4; ++ct) {
        const int rB = ct * 16 + m15;
        int pb = l + (rB % 24); if (pb >= 24) pb -= 24;
        bf16x8 b = *(const bf16x8*)&Bl[rB * 192 + pb * 8];
        acc[ct] = __builtin_amdgcn_mfma_f32_16x16x32_bf16(a0, b, acc[ct], 0, 0, 0);
      }
    }
    #pragma unroll
    for (int ct = 0; ct < 4; ++ct)
      #pragma unroll
      for (int i = 0; i < 4; ++i) {
        long row = mBase + wv * 16 + quad * 4 + i;
        int col = nt * 64 + ct * 16 + m15;
        float v = acc[ct][i] + bias[col];
        if (EPI == 1) {
          v += addin[row * N + col];
          ((float*)outp)[row * N + col] = v;
        } else {
          ((__hip_bfloat16*)outp)[row * N + col] = __float2bfloat16(v);
        }
      }
  }
}

// ===== GEMM variant A + INPUT LayerNorm (fused ln1): reads x f32, computes
// ===== row-LN in registers (4 threads/row, shfl_xor reduce), ds_writes bf16
// ===== into the SAME 24-slot rotation-swizzled Al layout.  Replaces the
// ===== standalone ln_kernel + its xn round-trip (-38.6 MB HBM / chunk). ====
__global__ __launch_bounds__(512, 4) void gemmA_lnin_kernel(
    const float* __restrict__ X, const float* __restrict__ lng,
    const float* __restrict__ lnb, const ushort* __restrict__ W,
    const float* __restrict__ bias, __hip_bfloat16* __restrict__ outp, int N)
{
  __shared__ __align__(16) ushort Al[128 * 192];
  __shared__ __align__(16) ushort Bl[64 * 192];
  const int tid = threadIdx.x;
  const int wv = tid >> 6;
  const int lane = tid & 63;
  const int quad = lane >> 4;
  const int m15 = lane & 15;
  const long mBase = (long)blockIdx.y * 128;
  const int NT = N >> 6;

  // ---- A stage: x f32 -> LN -> bf16 -> Al (rotation swizzle) ----
  {
    const int arow = tid >> 2;        // 0..127
    const int aseg = tid & 3;         // cols aseg*48 .. +47
    const float* xr = X + (mBase + arow) * 192 + aseg * 48;
    f32x4 xv[12];
    #pragma unroll
    for (int i = 0; i < 12; ++i) xv[i] = *(const f32x4*)(xr + i * 4);
    float s = 0.f, sq = 0.f;
    #pragma unroll
    for (int i = 0; i < 12; ++i)
      #pragma unroll
      for (int j = 0; j < 4; ++j) { s += xv[i][j]; sq += xv[i][j] * xv[i][j]; }
    s += __shfl_xor(s, 1, 64);  sq += __shfl_xor(sq, 1, 64);
    s += __shfl_xor(s, 2, 64);  sq += __shfl_xor(sq, 2, 64);
    const float mean = s * (1.0f / 192.0f);
    const float rstd = rsqrtf(sq * (1.0f / 192.0f) - mean * mean + 1e-5f);
    const int r24 = arow % 24;
    #pragma unroll
    for (int g6 = 0; g6 < 6; ++g6) {
      const int g = aseg * 6 + g6;            // logical 8-col chunk
      int cs = g + r24; if (cs >= 24) cs -= 24;
      u32x4 pk;
      #pragma unroll
      for (int u = 0; u < 2; ++u) {
        f32x4 v = xv[g6 * 2 + u];
        f32x4 gv = *(const f32x4*)(lng + g * 8 + u * 4);
        f32x4 bv = *(const f32x4*)(lnb + g * 8 + u * 4);
        float n0 = (v[0] - mean) * rstd * gv[0] + bv[0];
        float n1 = (v[1] - mean) * rstd * gv[1] + bv[1];
        float n2 = (v[2] - mean) * rstd * gv[2] + bv[2];
        float n3 = (v[3] - mean) * rstd * gv[3] + bv[3];
        unsigned lo, hi;
        asm("v_cvt_pk_bf16_f32 %0, %1, %2" : "=v"(lo) : "v"(n0), "v"(n1));
        asm("v_cvt_pk_bf16_f32 %0, %1, %2" : "=v"(hi) : "v"(n2), "v"(n3));
        pk[u * 2] = lo; pk[u * 2 + 1] = hi;
      }
      *(u32x4*)&Al[arow * 192 + cs * 8] = pk;
    }
  }

  const int rA0 = wv * 16 + m15;
  const int rA0m = rA0 % 24;

  for (int nt = 0; nt < NT; ++nt) {
    __syncthreads();   // drains A ds_writes (first iter) + prior B reads
    #pragma unroll
    for (int r = 0; r < 3; ++r) {
      int sI = tid + r * 512;
      int row = sI / 24;
      int cs = sI - row * 24;
      int gc = cs - (row % 24); if (gc < 0) gc += 24;
      gload_lds16(W + (long)(nt * 64 + row) * 192 + gc * 8, Bl + sI * 8);
    }
    __syncthreads();

    f32x4 acc[4];
    #pragma unroll
    for (int c = 0; c < 4; ++c) acc[c] = (f32x4){0.f, 0.f, 0.f, 0.f};

    #pragma unroll
    for (int ks = 0; ks < 6; ++ks) {
      const int l = ks * 4 + quad;
      int pa0 = l + rA0m; if (pa0 >= 24) pa0 -= 24;
      bf16x8 a0 = *(const bf16x8*)&Al[rA0 * 192 + pa0 * 8];
      #pragma unroll
      for (int ct = 0; ct < 4; ++ct) {
        const int rB = ct * 16 + m15;
        int pb = l + (rB % 24); if (pb >= 24) pb -= 24;
        bf16x8 b = *(const bf16x8*)&Bl[rB * 192 + pb * 8];
        acc[ct] = __builtin_amdgcn_mfma_f32_16x16x32_bf16(a0, b, acc[ct], 0, 0, 0);
      }
    }
    #pragma unroll
    for (int ct = 0; ct < 4; ++ct)
      #pragma unroll
      for (int i = 0; i < 4; ++i) {
        long row = mBase + wv * 16 + quad * 4 + i;
        int col = nt * 64 + ct * 16 + m15;
        outp[row * N + col] = __float2bfloat16(acc[ct][i] + bias[col]);
      }
  }
}

// ===== GEMM variant A+LN: proj with residual add, f32 out, fused LN ========
__global__ __launch_bounds__(512, 4) void gemmA_ln_kernel(
    const ushort* __restrict__ X, int lda, const ushort* __restrict__ W,
    const float* __restrict__ bias, const float* __restrict__ addin,
    float* __restrict__ outp, const float* __restrict__ lng,
    const float* __restrict__ lnb, __hip_bfloat16* __restrict__ xnout)
{
  __shared__ __align__(16) ushort Al[128 * 192];
  __shared__ __align__(16) ushort Bl[64 * 192];
  const int tid = threadIdx.x;
  const int wv = tid >> 6;
  const int lane = tid & 63;
  const int quad = lane >> 4;
  const int m15 = lane & 15;
  const long mBase = (long)blockIdx.y * 128;

  #pragma unroll
  for (int r = 0; r < 6; ++r) {
    int sI = tid + r * 512;
    int row = sI / 24;
    int cs = sI - row * 24;
    int gc = cs - (row % 24); if (gc < 0) gc += 24;
    gload_lds16(X + (mBase + row) * (long)lda + gc * 8, Al + sI * 8);
  }

  const int rA0 = wv * 16 + m15;
  const int rA0m = rA0 % 24;

  f32x4 acc[3][4];
  #pragma unroll
  for (int n = 0; n < 3; ++n)
    #pragma unroll
    for (int c = 0; c < 4; ++c) acc[n][c] = (f32x4){0.f, 0.f, 0.f, 0.f};

  #pragma unroll
  for (int nt = 0; nt < 3; ++nt) {
    __syncthreads();
    #pragma unroll
    for (int r = 0; r < 3; ++r) {
      int sI = tid + r * 512;
      int row = sI / 24;
      int cs = sI - row * 24;
      int gc = cs - (row % 24); if (gc < 0) gc += 24;
      gload_lds16(W + (long)(nt * 64 + row) * 192 + gc * 8, Bl + sI * 8);
    }
    __syncthreads();
    #pragma unroll
    for (int ks = 0; ks < 6; ++ks) {
      const int l = ks * 4 + quad;
      int pa0 = l + rA0m; if (pa0 >= 24) pa0 -= 24;
      bf16x8 a0 = *(const bf16x8*)&Al[rA0 * 192 + pa0 * 8];
      #pragma unroll
      for (int ct = 0; ct < 4; ++ct) {
        const int rB = ct * 16 + m15;
        int pb = l + (rB % 24); if (pb >= 24) pb -= 24;
        bf16x8 b = *(const bf16x8*)&Bl[rB * 192 + pb * 8];
        acc[nt][ct] = __builtin_amdgcn_mfma_f32_16x16x32_bf16(a0, b, acc[nt][ct], 0, 0, 0);
      }
    }
  }

  float sum_[4], sq_[4];
  #pragma unroll
  for (int i = 0; i < 4; ++i) { sum_[i] = 0.f; sq_[i] = 0.f; }

  #pragma unroll
  for (int nt = 0; nt < 3; ++nt)
    #pragma unroll
    for (int ct = 0; ct < 4; ++ct) {
      int col = nt * 64 + ct * 16 + m15;
      float cb = bias[col];
      #pragma unroll
      for (int i = 0; i < 4; ++i) {
        long row = mBase + wv * 16 + quad * 4 + i;
        float v = acc[nt][ct][i] + cb + addin[row * 192 + col];
        outp[row * 192 + col] = v;
        acc[nt][ct][i] = v;
        sum_[i] += v;
        sq_[i] += v * v;
      }
    }

  float mean_[4], rstd_[4];
  #pragma unroll
  for (int i = 0; i < 4; ++i) {
    float s = sum_[i], q = sq_[i];
    #pragma unroll
    for (int m = 1; m < 16; m <<= 1) {
      s += __shfl_xor(s, m, 64);
      q += __shfl_xor(q, m, 64);
    }
    float mean = s * (1.0f / 192.0f);
    mean_[i] = mean;
    rstd_[i] = rsqrtf(q * (1.0f / 192.0f) - mean * mean + 1e-5f);
  }

  #pragma unroll
  for (int nt = 0; nt < 3; ++nt)
    #pragma unroll
    for (int ct = 0; ct < 4; ++ct) {
      int col = nt * 64 + ct * 16 + m15;
      float cg = lng[col], cbb = lnb[col];
      #pragma unroll
      for (int i = 0; i < 4; ++i) {
        long row = mBase + wv * 16 + quad * 4 + i;
        float v = (acc[nt][ct][i] - mean_[i]) * rstd_[i] * cg + cbb;
        xnout[row * 192 + col] = __float2bfloat16(v);
      }
    }
}

// ===== GEMM variant B: fc2 (K=768, N=192). 4 K-chunks, 3 live n-tile accs ==
__global__ __launch_bounds__(512, 4) void gemmB_kernel(
    const ushort* __restrict__ X, const ushort* __restrict__ W,
    const float* __restrict__ bias, const float* __restrict__ addin,
    float* __restrict__ outp)
{
  __shared__ __align__(16) ushort Al[128 * 192];
  __shared__ __align__(16) ushort Bl[64 * 192];
  const int tid = threadIdx.x;
  const int wv = tid >> 6;
  const int lane = tid & 63;
  const int quad = lane >> 4;
  const int m15 = lane & 15;
  const long mBase = (long)blockIdx.y * 128;

  const int rA0 = wv * 16 + m15;
  const int rA0m = rA0 % 24;

  f32x4 acc[3][4];
  #pragma unroll
  for (int n = 0; n < 3; ++n)
    #pragma unroll
    for (int c = 0; c < 4; ++c) acc[n][c] = (f32x4){0.f, 0.f, 0.f, 0.f};

  for (int kc = 0; kc < 4; ++kc) {
    for (int nt = 0; nt < 3; ++nt) {
      __syncthreads();
      if (nt == 0) {
        #pragma unroll
        for (int r = 0; r < 6; ++r) {
          int sI = tid + r * 512;
          int row = sI / 24;
          int cs = sI - row * 24;
          int gc = cs - (row % 24); if (gc < 0) gc += 24;
          gload_lds16(X + (mBase + row) * 768l + kc * 192 + gc * 8, Al + sI * 8);
        }
      }
      #pragma unroll
      for (int r = 0; r < 3; ++r) {
        int sI = tid + r * 512;
        int row = sI / 24;
        int cs = sI - row * 24;
        int gc = cs - (row % 24); if (gc < 0) gc += 24;
        gload_lds16(W + (long)(nt * 64 + row) * 768 + kc * 192 + gc * 8, Bl + sI * 8);
      }
      __syncthreads();
      #pragma unroll
      for (int ks = 0; ks < 6; ++ks) {
        const int l = ks * 4 + quad;
        int pa0 = l + rA0m; if (pa0 >= 24) pa0 -= 24;
        bf16x8 a0 = *(const bf16x8*)&Al[rA0 * 192 + pa0 * 8];
        #pragma unroll
        for (int ct = 0; ct < 4; ++ct) {
          const int rB = ct * 16 + m15;
          int pb = l + (rB % 24); if (pb >= 24) pb -= 24;
          bf16x8 b = *(const bf16x8*)&Bl[rB * 192 + pb * 8];
          acc[nt][ct] = __builtin_amdgcn_mfma_f32_16x16x32_bf16(a0, b, acc[nt][ct], 0, 0, 0);
        }
      }
    }
  }
  #pragma unroll
  for (int nt = 0; nt < 3; ++nt)
    #pragma unroll
    for (int ct = 0; ct < 4; ++ct)
      #pragma unroll
      for (int i = 0; i < 4; ++i) {
        long row = mBase + wv * 16 + quad * 4 + i;
        int col = nt * 64 + ct * 16 + m15;
        float v = acc[nt][ct][i] + bias[col] + addin[row * 192 + col];
        outp[row * 192 + col] = v;
      }
}

// ============ window attention: MFMA version, one wave per window-head ======
__global__ __launch_bounds__(256, 3) void attn_kernel(
    const float* __restrict__ rpe, __hip_bfloat16* __restrict__ qkv)
{
  __shared__ __align__(16) char smem[51968];
  const int tid = threadIdx.x;
  const int lane = tid & 63;
  const int wv = tid >> 6;
  const int quad = lane >> 4;
  const int m15 = lane & 15;
  const int wh = blockIdx.x * 4 + wv;
  const int h = wh & 7;
  const int win = wh >> 3;
  const int b = win >> 8;
  const int wl = win & 255;
  const int whi = wl >> 4;
  const int wwi = wl & 15;
  ushort* qkv_u = (ushort*)qkv;
  char* Vb = smem + wv * 4096;                       // V: [64 j][32 d] bf16
  char* Pb = smem + 16384 + wv * 8192;               // P: [64 r][64 j] bf16
  float* biasW = (float*)(smem + 49152 + wv * 704);  // 169 f32

  const long rowbase = (long)b * 12544 + (long)(whi * 7) * 112 + wwi * 7;

  // ---- stage V rows (swizzled) ; zero pad rows 49..63 (K-dim safety) ----
  {
    int j = lane;
    int f = ((j >> 3) & 3) << 5;
    if (j < 49) {
      int py = j / 7, px = j - py * 7;
      long row = rowbase + py * 112 + px;
      const ushort* src = qkv_u + row * 576 + 384 + h * 24;
      #pragma unroll
      for (int c = 0; c < 3; ++c) {
        u16x8 val = *(const u16x8*)(src + c * 8);
        *(u16x8*)(Vb + ((j * 64 + c * 16) ^ f)) = val;
      }
    } else {
      u16x8 z = {};
      #pragma unroll
      for (int c = 0; c < 4; ++c)
        *(u16x8*)(Vb + ((j * 64 + c * 16) ^ f)) = z;
    }
  }
  for (int r = lane; r < 169; r += 64) biasW[r] = rpe[r * 8 + h];

  // ---- relative-position index components ----
  int bi[4];
  #pragma unroll
  for (int rt = 0; rt < 4; ++rt) {
    int r = rt * 16 + m15; if (r > 48) r = 48;
    bi[rt] = (r / 7) * 13 + (r % 7) + 84;
  }
  int bj4[4][4];
  #pragma unroll
  for (int jt = 0; jt < 4; ++jt)
    #pragma unroll
    for (int i = 0; i < 4; ++i) {
      int j = jt * 16 + quad * 4 + i; if (j > 48) j = 48;
      bj4[jt][i] = (j / 7) * 13 + (j % 7);
    }

  // ---- S^T accumulators, bias as C-in ----
  f32x4 sacc[4][4];  // [jt][rt]
  #pragma unroll
  for (int jt = 0; jt < 4; ++jt)
    #pragma unroll
    for (int rt = 0; rt < 4; ++rt)
      #pragma unroll
      for (int i = 0; i < 4; ++i)
        sacc[jt][rt][i] = biasW[bi[rt] - bj4[jt][i]];

  // ---- K / Q fragments straight from global ----
  bf16x8 kf[4], qf[4];
  const bf16x8 zf = {};
  #pragma unroll
  for (int jt = 0; jt < 4; ++jt) {
    int t = jt * 16 + m15; if (t > 48) t = 48;
    long row = rowbase + (t / 7) * 112 + (t % 7);
    kf[jt] = *(const bf16x8*)(qkv_u + row * 576 + 192 + h * 24 + quad * 8);
    if (quad == 3) kf[jt] = zf;   // zero d=24..31 pad (one side zero -> ok)
  }
  #pragma unroll
  for (int rt = 0; rt < 4; ++rt) {
    int t = rt * 16 + m15; if (t > 48) t = 48;
    long row = rowbase + (t / 7) * 112 + (t % 7);
    qf[rt] = *(const bf16x8*)(qkv_u + row * 576 + h * 24 + quad * 8);
  }
  #pragma unroll
  for (int jt = 0; jt < 4; ++jt)
    #pragma unroll
    for (int rt = 0; rt < 4; ++rt)
      sacc[jt][rt] = __builtin_amdgcn_mfma_f32_16x16x32_bf16(
          kf[jt], qf[rt], sacc[jt][rt], 0, 0, 0);

  // ---- mask j >= 49 (jt=3: j = 48 + quad*4 + i) ----
  #pragma unroll
  for (int rt = 0; rt < 4; ++rt) {
    if (quad != 0) sacc[3][rt][0] = -1e30f;
    sacc[3][rt][1] = -1e30f;
    sacc[3][rt][2] = -1e30f;
    sacc[3][rt][3] = -1e30f;
  }

  // ---- softmax over j per r-column (unnormalized; inv kept per rt) ----
  float inv[4];
  #pragma unroll
  for (int rt = 0; rt < 4; ++rt) {
    float mx = sacc[0][rt][0];
    #pragma unroll
    for (int jt = 0; jt < 4; ++jt)
      #pragma unroll
      for (int i = 0; i < 4; ++i)
        mx = fmaxf(mx, sacc[jt][rt][i]);
    mx = fmaxf(mx, __shfl_xor(mx, 16, 64));
    mx = fmaxf(mx, __shfl_xor(mx, 32, 64));
    float sum = 0.f;
    #pragma unroll
    for (int jt = 0; jt < 4; ++jt)
      #pragma unroll
      for (int i = 0; i < 4; ++i) {
        float p = __expf(sacc[jt][rt][i] - mx);
        sacc[jt][rt][i] = p;
        sum += p;
      }
    sum += __shfl_xor(sum, 16, 64);
    sum += __shfl_xor(sum, 32, 64);
    inv[rt] = 1.f / sum;
  }

  // ---- P -> bf16 -> swizzled LDS ([64 r][64 j], byte ^= (m15&7)<<4) ----
  const int swzP = (m15 & 7) << 4;
  #pragma unroll
  for (int rt = 0; rt < 4; ++rt)
    #pragma unroll
    for (int jt = 0; jt < 4; ++jt)
      #pragma unroll
      for (int u = 0; u < 2; ++u) {
        unsigned pk;
        asm("v_cvt_pk_bf16_f32 %0, %1, %2"
            : "=v"(pk)
            : "v"(sacc[jt][rt][2 * u]), "v"(sacc[jt][rt][2 * u + 1]));
        int j0 = jt * 16 + quad * 4 + 2 * u;
        int lin = (rt * 16 + m15) * 128 + j0 * 2;
        *(unsigned*)(Pb + (lin ^ swzP)) = pk;
      }

  // ---- O = P.V ----
  f32x4 oacc[4][2];
  #pragma unroll
  for (int mt = 0; mt < 4; ++mt)
    #pragma unroll
    for (int nt = 0; nt < 2; ++nt) oacc[mt][nt] = (f32x4){0.f, 0.f, 0.f, 0.f};

  #pragma unroll
  for (int kt = 0; kt < 2; ++kt) {
    bf16x8 pf[4];
    #pragma unroll
    for (int mt = 0; mt < 4; ++mt) {
      int lin = (mt * 16 + m15) * 128 + kt * 64 + quad * 16;
      pf[mt] = *(const bf16x8*)(Pb + (lin ^ swzP));
    }
    bf16x8 vf[2];
    #pragma unroll
    for (int nt = 0; nt < 2; ++nt) {
      u32x4 w;
      #pragma unroll
      for (int e2 = 0; e2 < 4; ++e2) {
        int j_lo = kt * 32 + quad * 8 + 2 * e2;
        int lin_lo = j_lo * 64 + (nt * 16 + m15) * 2;
        int lin_hi = lin_lo + 64;
        unsigned lo = *(const ushort*)(Vb + (lin_lo ^ (quad << 5)));
        unsigned hi = *(const ushort*)(Vb + (lin_hi ^ (quad << 5)));
        w[e2] = lo | (hi << 16);
      }
      vf[nt] = __builtin_bit_cast(bf16x8, w);
    }
    #pragma unroll
    for (int mt = 0; mt < 4; ++mt)
      #pragma unroll
      for (int nt = 0; nt < 2; ++nt)
        oacc[mt][nt] = __builtin_amdgcn_mfma_f32_16x16x32_bf16(
            pf[mt], vf[nt], oacc[mt][nt], 0, 0, 0);
  }

  // ---- normalize (redistribute inv via bpermute) + store ----
  #pragma unroll
  for (int mt = 0; mt < 4; ++mt)
    #pragma unroll
    for (int i = 0; i < 4; ++i) {
      float iv = __shfl(inv[mt], quad * 4 + i, 64);
      int r = mt * 16 + quad * 4 + i;
      if (r < 49) {
        long row = rowbase + (r / 7) * 112 + (r % 7);
        ushort* dst = qkv_u + row * 576 + h * 24;
        dst[m15] = f2bfu(oacc[mt][0][i] * iv);
        if (m15 < 8) dst[16 + m15] = f2bfu(oacc[mt][1][i] * iv);
      }
    }
}

// -------- depthwise 3x3 conv + bias + tanh-GELU, 2 rows/iter, deep ring -----
// R6: VALUBusy 32% + occ 54% -> still waitcnt-stalled; FETCH showed 10%
// wasted prefetch (rows loaded at m=7, never used).  Now: 8-slot named
// window; prefetch issued at iter m is consumed at iter m+2 (~700 cyc
// slack vs HBM ~500-900), gated with m<6 so no wasted rows.
__global__ __launch_bounds__(384, 8) void dwconv_gelu_kernel(
    const ushort* __restrict__ y1, const float* __restrict__ w,
    const float* __restrict__ bias, ushort* __restrict__ y2)
{
  const int c = threadIdx.x * 2;       // channel pair
  const int w0 = blockIdx.y * 2;       // output cols w0, w0+1
  const int b = blockIdx.z;
  const int h0 = blockIdx.x * 16;

  f32x2 wt[9];
  #pragma unroll
  for (int k = 0; k < 9; ++k)
    wt[k] = (f32x2){w[(c + 0) * 9 + k], w[(c + 1) * 9 + k]};
  const f32x2 bs = (f32x2){bias[c], bias[c + 1]};

  const bool okL = (w0 > 0), okR = (w0 + 2 < 112);

  uint rA[4], rB[4], rC[4], rD[4], rE[4], rF[4], rG[4], rH[4];

  auto loadrow = [&](int h, uint dst[4]) {
    if (h < 0 || h >= 112) {
      dst[0] = 0u; dst[1] = 0u; dst[2] = 0u; dst[3] = 0u;
      return;
    }
    const ushort* p = y1 + (((size_t)(b * 112 + h)) * 112 + w0) * HID + c;
    dst[0] = okL ? *(const uint*)(p - HID) : 0u;
    dst[1] = *(const uint*)(p);
    dst[2] = *(const uint*)(p + HID);
    dst[3] = okR ? *(const uint*)(p + 2 * HID) : 0u;
  };

  auto taps = [&](const uint r[4], int k0, f32x2& p0, f32x2& p1) {
    #pragma unroll
    for (int x = 0; x < 4; ++x) {
      f32x2 col = (f32x2){__uint_as_float(r[x] << 16),
                          __uint_as_float(r[x] & 0xffff0000u)};
      if (x < 3) p0 += wt[k0 + x] * col;
      if (x > 0) p1 += wt[k0 + x - 1] * col;
    }
  };

  auto emit = [&](f32x2 a0, f32x2 a1, int h) {
    ushort* outp = y2 + (((size_t)(b * 112 + h)) * 112 + w0) * HID + c;
    unsigned q0, q1;
    float g0 = fgelu(a0[0]), g1 = fgelu(a0[1]);
    float g2 = fgelu(a1[0]), g3 = fgelu(a1[1]);
    asm("v_cvt_pk_bf16_f32 %0, %1, %2" : "=v"(q0) : "v"(g0), "v"(g1));
    asm("v_cvt_pk_bf16_f32 %0, %1, %2" : "=v"(q1) : "v"(g2), "v"(g3));
    *(uint*)(outp) = q0;
    *(uint*)(outp + HID) = q1;
  };

  loadrow(h0 - 1, rA);
  loadrow(h0,     rB);
  loadrow(h0 + 1, rC);
  loadrow(h0 + 2, rD);
  loadrow(h0 + 3, rE);
  loadrow(h0 + 4, rF);

  #pragma unroll
  for (int m = 0; m < 8; ++m) {
    const int h = h0 + 2 * m;
    // prefetch rows consumed at iteration m+2 (gated: no waste at the tail)
    if (m < 6) {
      loadrow(h + 5, rG);
      loadrow(h + 6, rH);
    }

    f32x2 a0 = bs, a1 = bs;      // output row h
    f32x2 b0 = bs, b1 = bs;      // output row h+1
    taps(rA, 0, a0, a1);
    taps(rB, 3, a0, a1);
    taps(rB, 0, b0, b1);
    taps(rC, 6, a0, a1);
    taps(rC, 3, b0, b1);
    taps(rD, 6, b0, b1);
    emit(a0, a1, h);
    emit(b0, b1, h + 1);

    #pragma unroll
    for (int x = 0; x < 4; ++x) {
      rA[x] = rC[x]; rB[x] = rD[x]; rC[x] = rE[x]; rD[x] = rF[x];
      rE[x] = rG[x]; rF[x] = rH[x];
    }
  }
}

// ---------------------------------------------------------------------------
extern "C" void kernel_launch(void* const* d_in, const int* in_sizes, int n_in,
                              void* d_out, int out_size, void* d_ws, size_t ws_size,
                              hipStream_t stream) {
  const float* x      = (const float*)d_in[0];
  const float* n1g    = (const float*)d_in[1];
  const float* n1b    = (const float*)d_in[2];
  const float* q_w    = (const float*)d_in[3];
  const float* q_b    = (const float*)d_in[4];
  const float* kv_w   = (const float*)d_in[5];
  const float* kv_b   = (const float*)d_in[6];
  const float* rpe    = (const float*)d_in[7];
  const float* proj_w = (const float*)d_in[8];
  const float* proj_b = (const float*)d_in[9];
  const float* n2g    = (const float*)d_in[10];
  const float* n2b    = (const float*)d_in[11];
  const float* fc1_w  = (const float*)d_in[12];
  const float* fc1_b  = (const float*)d_in[13];
  const float* dw_w   = (const float*)d_in[14];
  const float* dw_b   = (const float*)d_in[15];
  const float* fc2_w  = (const float*)d_in[16];
  const float* fc2_b  = (const float*)d_in[17];
  float* out = (float*)d_out;

  // ---- weights at front of ws (~0.9 MB) ----
  char* ws = (char*)d_ws;
  __hip_bfloat16* wcat  = (__hip_bfloat16*)(ws);               // 576*192 bf16
  __hip_bfloat16* projw = (__hip_bfloat16*)(ws + 221184);      // 192*192
  __hip_bfloat16* fc1w  = (__hip_bfloat16*)(ws + 294912);      // 768*192
  __hip_bfloat16* fc2w  = (__hip_bfloat16*)(ws + 589824);      // 192*768
  float* bcat           = (float*)(ws + 884736);               // 576 f32
  const size_t WOFF = 1u << 20;                                // 1 MB

  // ---- pick images-per-chunk CB so the activation buffers fit ws_size ----
  int CB = 8;
  while (CB > 1 && WOFF + (size_t)CB * 12544 * 3456 > ws_size) CB >>= 1;
  const size_t Mc = (size_t)CB * 12544;
  char* Abuf = ws + WOFF;                        // xn (bf16 Mc x 192)
  char* Bbuf = Abuf + Mc * 384;                  // qkv (Mc x 576) / y2 (Mc x 768)
  char* Cbuf = Bbuf + Mc * 1536;                 // y1 (bf16 Mc x 768)
  __hip_bfloat16* xn  = (__hip_bfloat16*)Abuf;
  __hip_bfloat16* qkv = (__hip_bfloat16*)Bbuf;
  __hip_bfloat16* y2  = (__hip_bfloat16*)Bbuf;
  __hip_bfloat16* y1  = (__hip_bfloat16*)Cbuf;

  prep_kernel<<<576, 256, 0, stream>>>(q_w, q_b, kv_w, kv_b, proj_w, fc1_w,
                                       fc2_w, wcat, bcat, projw, fc1w, fc2w);

  const int nChunks = 8 / CB;
  const int mt = CB * 98;
  for (int cchunk = 0; cchunk < nChunks; ++cchunk) {
    const size_t toff = (size_t)cchunk * Mc;
    const float* xc = x + toff * C_DIM;
    float* oc = out + toff * C_DIM;

    gemmA_lnin_kernel<<<dim3(1, mt), 512, 0, stream>>>(
        xc, n1g, n1b, (const ushort*)wcat, bcat, qkv, 576);
    attn_kernel<<<CB * 512, 256, 0, stream>>>(rpe, qkv);
    gemmA_ln_kernel<<<dim3(1, mt), 512, 0, stream>>>(
        (const ushort*)qkv, 576, (const ushort*)projw, proj_b, xc, oc,
        n2g, n2b, xn);
    gemmA_kernel<0><<<dim3(1, mt), 512, 0, stream>>>(
        (const ushort*)xn, 192, (const ushort*)fc1w, fc1_b, nullptr, y1, 768);
    dwconv_gelu_kernel<<<dim3(7, 56, CB), 384, 0, stream>>>(
        (const ushort*)y1, dw_w, dw_b, (ushort*)y2);
    gemmB_kernel<<<dim3(1, mt), 512, 0, stream>>>(
        (const ushort*)y2, (const ushort*)fc2w, fc2_b, oc, oc);
  }
}

// Round 8
// 559.719 us; speedup vs baseline: 1.0849x; 1.0849x over previous
//
#include <hip/hip_runtime.h>
#include <hip/hip_bf16.h>
#include <cmath>

// Problem constants (B=8, H=W=112, C=192, heads=8, hd=24, ps=7, hid=768)
#define C_DIM 192
#define HID 768

typedef __attribute__((ext_vector_type(8))) __bf16 bf16x8;
typedef __attribute__((ext_vector_type(4))) float f32x4;
typedef __attribute__((ext_vector_type(2))) float f32x2;
typedef __attribute__((ext_vector_type(8))) unsigned short u16x8;
typedef __attribute__((ext_vector_type(4))) unsigned int u32x4;

__device__ __forceinline__ void gload_lds16(const void* g, void* l) {
  __builtin_amdgcn_global_load_lds(
      (__attribute__((address_space(1))) void*)(const_cast<void*>(g)),
      (__attribute__((address_space(3))) void*)(l), 16, 0, 0);
}

__device__ __forceinline__ float bfu2f(ushort u) {
  return __uint_as_float((unsigned)u << 16);
}
__device__ __forceinline__ ushort f2bfu(float f) {
  __hip_bfloat16 h = __float2bfloat16(f);
  return *reinterpret_cast<ushort*>(&h);
}
// tanh-form GELU, exp2-folded + raw v_rcp (validated R6, absmax 0.0156)
__device__ __forceinline__ float fgelu(float x) {
  float z = x * (2.30226545f + 0.10293942f * x * x);  // (1.59577,0.0713548)*log2e
  float e = __builtin_amdgcn_exp2f(-z);
  return x * __builtin_amdgcn_rcpf(1.f + e);
}

// ---------------- prep: weights fp32 -> bf16 (+ fold q scale) ----------------
__global__ __launch_bounds__(256) void prep_kernel(
    const float* __restrict__ q_w, const float* __restrict__ q_b,
    const float* __restrict__ kv_w, const float* __restrict__ kv_b,
    const float* __restrict__ proj_w, const float* __restrict__ fc1_w,
    const float* __restrict__ fc2_w,
    __hip_bfloat16* __restrict__ wcat, float* __restrict__ bcat,
    __hip_bfloat16* __restrict__ projw, __hip_bfloat16* __restrict__ fc1w,
    __hip_bfloat16* __restrict__ fc2w)
{
  int idx = blockIdx.x * 256 + threadIdx.x;
  const float scale = 0.20412414523193154f;  // 24^-0.5
  if (idx < 110592) {
    float v = (idx < 36864) ? q_w[idx] * scale : kv_w[idx - 36864];
    wcat[idx] = __float2bfloat16(v);
  }
  if (idx < 576) bcat[idx] = (idx < 192) ? q_b[idx] * scale : kv_b[idx - 192];
  if (idx < 36864) projw[idx] = __float2bfloat16(proj_w[idx]);
  if (idx < 147456) {
    fc1w[idx] = __float2bfloat16(fc1_w[idx]);
    fc2w[idx] = __float2bfloat16(fc2_w[idx]);
  }
}

// ===== GEMM variant A: K=192, A-tile LDS-resident, serial n-tiles ===========
template <int EPI>
__global__ __launch_bounds__(512, 4) void gemmA_kernel(
    const ushort* __restrict__ X, int lda, const ushort* __restrict__ W,
    const float* __restrict__ bias, const float* __restrict__ addin,
    void* __restrict__ outp, int N)
{
  __shared__ __align__(16) ushort Al[128 * 192];  // 49152 B
  __shared__ __align__(16) ushort Bl[64 * 192];   // 24576 B
  const int tid = threadIdx.x;
  const int wv = tid >> 6;          // 0..7
  const int lane = tid & 63;
  const int quad = lane >> 4;
  const int m15 = lane & 15;
  const long mBase = (long)blockIdx.y * 128;
  const int NT = N >> 6;

  #pragma unroll
  for (int r = 0; r < 6; ++r) {
    int sI = tid + r * 512;
    int row = sI / 24;
    int cs = sI - row * 24;
    int gc = cs - (row % 24); if (gc < 0) gc += 24;
    gload_lds16(X + (mBase + row) * (long)lda + gc * 8, Al + sI * 8);
  }

  const int rA0 = wv * 16 + m15;
  const int rA0m = rA0 % 24;

  for (int nt = 0; nt < NT; ++nt) {
    __syncthreads();
    #pragma unroll
    for (int r = 0; r < 3; ++r) {
      int sI = tid + r * 512;
      int row = sI / 24;
      int cs = sI - row * 24;
      int gc = cs - (row % 24); if (gc < 0) gc += 24;
      gload_lds16(W + (long)(nt * 64 + row) * 192 + gc * 8, Bl + sI * 8);
    }
    __syncthreads();

    f32x4 acc[4];
    #pragma unroll
    for (int c = 0; c < 4; ++c) acc[c] = (f32x4){0.f, 0.f, 0.f, 0.f};

    #pragma unroll
    for (int ks = 0; ks < 6; ++ks) {
      const int l = ks * 4 + quad;
      int pa0 = l + rA0m; if (pa0 >= 24) pa0 -= 24;
      bf16x8 a0 = *(const bf16x8*)&Al[rA0 * 192 + pa0 * 8];
      #pragma unroll
      for (int ct = 0; ct < 4; ++ct) {
        const int rB = ct * 16 + m15;
        int pb = l + (rB % 24); if (pb >= 24) pb -= 24;
        bf16x8 b = *(const bf16x8*)&Bl[rB * 192 + pb * 8];
        acc[ct] = __builtin_amdgcn_mfma_f32_16x16x32_bf16(a0, b, acc[ct], 0, 0, 0);
      }
    }
    #pragma unroll
    for (int ct = 0; ct < 4; ++ct)
      #pragma unroll
      for (int i = 0; i < 4; ++i) {
        long row = mBase + wv * 16 + quad * 4 + i;
        int col = nt * 64 + ct * 16 + m15;
        float v = acc[ct][i] + bias[col];
        if (EPI == 1) {
          v += addin[row * N + col];
          ((float*)outp)[row * N + col] = v;
        } else {
          ((__hip_bfloat16*)outp)[row * N + col] = __float2bfloat16(v);
        }
      }
  }
}

// ===== GEMM variant A + INPUT LayerNorm (fused ln1): reads x f32, computes
// ===== row-LN in registers (4 threads/row, shfl_xor reduce), ds_writes bf16
// ===== into the SAME 24-slot rotation-swizzled Al layout. ==================
__global__ __launch_bounds__(512, 4) void gemmA_lnin_kernel(
    const float* __restrict__ X, const float* __restrict__ lng,
    const float* __restrict__ lnb, const ushort* __restrict__ W,
    const float* __restrict__ bias, __hip_bfloat16* __restrict__ outp, int N)
{
  __shared__ __align__(16) ushort Al[128 * 192];
  __shared__ __align__(16) ushort Bl[64 * 192];
  const int tid = threadIdx.x;
  const int wv = tid >> 6;
  const int lane = tid & 63;
  const int quad = lane >> 4;
  const int m15 = lane & 15;
  const long mBase = (long)blockIdx.y * 128;
  const int NT = N >> 6;

  // ---- A stage: x f32 -> LN -> bf16 -> Al (rotation swizzle) ----
  {
    const int arow = tid >> 2;        // 0..127
    const int aseg = tid & 3;         // cols aseg*48 .. +47
    const float* xr = X + (mBase + arow) * 192 + aseg * 48;
    f32x4 xv[12];
    #pragma unroll
    for (int i = 0; i < 12; ++i) xv[i] = *(const f32x4*)(xr + i * 4);
    float s = 0.f, sq = 0.f;
    #pragma unroll
    for (int i = 0; i < 12; ++i)
      #pragma unroll
      for (int j = 0; j < 4; ++j) { s += xv[i][j]; sq += xv[i][j] * xv[i][j]; }
    s += __shfl_xor(s, 1, 64);  sq += __shfl_xor(sq, 1, 64);
    s += __shfl_xor(s, 2, 64);  sq += __shfl_xor(sq, 2, 64);
    const float mean = s * (1.0f / 192.0f);
    const float rstd = rsqrtf(sq * (1.0f / 192.0f) - mean * mean + 1e-5f);
    const int r24 = arow % 24;
    #pragma unroll
    for (int g6 = 0; g6 < 6; ++g6) {
      const int g = aseg * 6 + g6;            // logical 8-col chunk
      int cs = g + r24; if (cs >= 24) cs -= 24;
      u32x4 pk;
      #pragma unroll
      for (int u = 0; u < 2; ++u) {
        f32x4 v = xv[g6 * 2 + u];
        f32x4 gv = *(const f32x4*)(lng + g * 8 + u * 4);
        f32x4 bv = *(const f32x4*)(lnb + g * 8 + u * 4);
        float n0 = (v[0] - mean) * rstd * gv[0] + bv[0];
        float n1 = (v[1] - mean) * rstd * gv[1] + bv[1];
        float n2 = (v[2] - mean) * rstd * gv[2] + bv[2];
        float n3 = (v[3] - mean) * rstd * gv[3] + bv[3];
        unsigned lo, hi;
        asm("v_cvt_pk_bf16_f32 %0, %1, %2" : "=v"(lo) : "v"(n0), "v"(n1));
        asm("v_cvt_pk_bf16_f32 %0, %1, %2" : "=v"(hi) : "v"(n2), "v"(n3));
        pk[u * 2] = lo; pk[u * 2 + 1] = hi;
      }
      *(u32x4*)&Al[arow * 192 + cs * 8] = pk;
    }
  }

  const int rA0 = wv * 16 + m15;
  const int rA0m = rA0 % 24;

  for (int nt = 0; nt < NT; ++nt) {
    __syncthreads();   // drains A ds_writes (first iter) + prior B reads
    #pragma unroll
    for (int r = 0; r < 3; ++r) {
      int sI = tid + r * 512;
      int row = sI / 24;
      int cs = sI - row * 24;
      int gc = cs - (row % 24); if (gc < 0) gc += 24;
      gload_lds16(W + (long)(nt * 64 + row) * 192 + gc * 8, Bl + sI * 8);
    }
    __syncthreads();

    f32x4 acc[4];
    #pragma unroll
    for (int c = 0; c < 4; ++c) acc[c] = (f32x4){0.f, 0.f, 0.f, 0.f};

    #pragma unroll
    for (int ks = 0; ks < 6; ++ks) {
      const int l = ks * 4 + quad;
      int pa0 = l + rA0m; if (pa0 >= 24) pa0 -= 24;
      bf16x8 a0 = *(const bf16x8*)&Al[rA0 * 192 + pa0 * 8];
      #pragma unroll
      for (int ct = 0; ct < 4; ++ct) {
        const int rB = ct * 16 + m15;
        int pb = l + (rB % 24); if (pb >= 24) pb -= 24;
        bf16x8 b = *(const bf16x8*)&Bl[rB * 192 + pb * 8];
        acc[ct] = __builtin_amdgcn_mfma_f32_16x16x32_bf16(a0, b, acc[ct], 0, 0, 0);
      }
    }
    #pragma unroll
    for (int ct = 0; ct < 4; ++ct)
      #pragma unroll
      for (int i = 0; i < 4; ++i) {
        long row = mBase + wv * 16 + quad * 4 + i;
        int col = nt * 64 + ct * 16 + m15;
        outp[row * N + col] = __float2bfloat16(acc[ct][i] + bias[col]);
      }
  }
}

// ===== GEMM variant A+LN: proj with residual add, f32 out, fused LN ========
__global__ __launch_bounds__(512, 4) void gemmA_ln_kernel(
    const ushort* __restrict__ X, int lda, const ushort* __restrict__ W,
    const float* __restrict__ bias, const float* __restrict__ addin,
    float* __restrict__ outp, const float* __restrict__ lng,
    const float* __restrict__ lnb, __hip_bfloat16* __restrict__ xnout)
{
  __shared__ __align__(16) ushort Al[128 * 192];
  __shared__ __align__(16) ushort Bl[64 * 192];
  const int tid = threadIdx.x;
  const int wv = tid >> 6;
  const int lane = tid & 63;
  const int quad = lane >> 4;
  const int m15 = lane & 15;
  const long mBase = (long)blockIdx.y * 128;

  #pragma unroll
  for (int r = 0; r < 6; ++r) {
    int sI = tid + r * 512;
    int row = sI / 24;
    int cs = sI - row * 24;
    int gc = cs - (row % 24); if (gc < 0) gc += 24;
    gload_lds16(X + (mBase + row) * (long)lda + gc * 8, Al + sI * 8);
  }

  const int rA0 = wv * 16 + m15;
  const int rA0m = rA0 % 24;

  f32x4 acc[3][4];
  #pragma unroll
  for (int n = 0; n < 3; ++n)
    #pragma unroll
    for (int c = 0; c < 4; ++c) acc[n][c] = (f32x4){0.f, 0.f, 0.f, 0.f};

  #pragma unroll
  for (int nt = 0; nt < 3; ++nt) {
    __syncthreads();
    #pragma unroll
    for (int r = 0; r < 3; ++r) {
      int sI = tid + r * 512;
      int row = sI / 24;
      int cs = sI - row * 24;
      int gc = cs - (row % 24); if (gc < 0) gc += 24;
      gload_lds16(W + (long)(nt * 64 + row) * 192 + gc * 8, Bl + sI * 8);
    }
    __syncthreads();
    #pragma unroll
    for (int ks = 0; ks < 6; ++ks) {
      const int l = ks * 4 + quad;
      int pa0 = l + rA0m; if (pa0 >= 24) pa0 -= 24;
      bf16x8 a0 = *(const bf16x8*)&Al[rA0 * 192 + pa0 * 8];
      #pragma unroll
      for (int ct = 0; ct < 4; ++ct) {
        const int rB = ct * 16 + m15;
        int pb = l + (rB % 24); if (pb >= 24) pb -= 24;
        bf16x8 b = *(const bf16x8*)&Bl[rB * 192 + pb * 8];
        acc[nt][ct] = __builtin_amdgcn_mfma_f32_16x16x32_bf16(a0, b, acc[nt][ct], 0, 0, 0);
      }
    }
  }

  float sum_[4], sq_[4];
  #pragma unroll
  for (int i = 0; i < 4; ++i) { sum_[i] = 0.f; sq_[i] = 0.f; }

  #pragma unroll
  for (int nt = 0; nt < 3; ++nt)
    #pragma unroll
    for (int ct = 0; ct < 4; ++ct) {
      int col = nt * 64 + ct * 16 + m15;
      float cb = bias[col];
      #pragma unroll
      for (int i = 0; i < 4; ++i) {
        long row = mBase + wv * 16 + quad * 4 + i;
        float v = acc[nt][ct][i] + cb + addin[row * 192 + col];
        outp[row * 192 + col] = v;
        acc[nt][ct][i] = v;
        sum_[i] += v;
        sq_[i] += v * v;
      }
    }

  float mean_[4], rstd_[4];
  #pragma unroll
  for (int i = 0; i < 4; ++i) {
    float s = sum_[i], q = sq_[i];
    #pragma unroll
    for (int m = 1; m < 16; m <<= 1) {
      s += __shfl_xor(s, m, 64);
      q += __shfl_xor(q, m, 64);
    }
    float mean = s * (1.0f / 192.0f);
    mean_[i] = mean;
    rstd_[i] = rsqrtf(q * (1.0f / 192.0f) - mean * mean + 1e-5f);
  }

  #pragma unroll
  for (int nt = 0; nt < 3; ++nt)
    #pragma unroll
    for (int ct = 0; ct < 4; ++ct) {
      int col = nt * 64 + ct * 16 + m15;
      float cg = lng[col], cbb = lnb[col];
      #pragma unroll
      for (int i = 0; i < 4; ++i) {
        long row = mBase + wv * 16 + quad * 4 + i;
        float v = (acc[nt][ct][i] - mean_[i]) * rstd_[i] * cg + cbb;
        xnout[row * 192 + col] = __float2bfloat16(v);
      }
    }
}

// ===== GEMM variant B: fc2 (K=768, N=192). 4 K-chunks, 3 live n-tile accs ==
__global__ __launch_bounds__(512, 4) void gemmB_kernel(
    const ushort* __restrict__ X, const ushort* __restrict__ W,
    const float* __restrict__ bias, const float* __restrict__ addin,
    float* __restrict__ outp)
{
  __shared__ __align__(16) ushort Al[128 * 192];
  __shared__ __align__(16) ushort Bl[64 * 192];
  const int tid = threadIdx.x;
  const int wv = tid >> 6;
  const int lane = tid & 63;
  const int quad = lane >> 4;
  const int m15 = lane & 15;
  const long mBase = (long)blockIdx.y * 128;

  const int rA0 = wv * 16 + m15;
  const int rA0m = rA0 % 24;

  f32x4 acc[3][4];
  #pragma unroll
  for (int n = 0; n < 3; ++n)
    #pragma unroll
    for (int c = 0; c < 4; ++c) acc[n][c] = (f32x4){0.f, 0.f, 0.f, 0.f};

  for (int kc = 0; kc < 4; ++kc) {
    for (int nt = 0; nt < 3; ++nt) {
      __syncthreads();
      if (nt == 0) {
        #pragma unroll
        for (int r = 0; r < 6; ++r) {
          int sI = tid + r * 512;
          int row = sI / 24;
          int cs = sI - row * 24;
          int gc = cs - (row % 24); if (gc < 0) gc += 24;
          gload_lds16(X + (mBase + row) * 768l + kc * 192 + gc * 8, Al + sI * 8);
        }
      }
      #pragma unroll
      for (int r = 0; r < 3; ++r) {
        int sI = tid + r * 512;
        int row = sI / 24;
        int cs = sI - row * 24;
        int gc = cs - (row % 24); if (gc < 0) gc += 24;
        gload_lds16(W + (long)(nt * 64 + row) * 768 + kc * 192 + gc * 8, Bl + sI * 8);
      }
      __syncthreads();
      #pragma unroll
      for (int ks = 0; ks < 6; ++ks) {
        const int l = ks * 4 + quad;
        int pa0 = l + rA0m; if (pa0 >= 24) pa0 -= 24;
        bf16x8 a0 = *(const bf16x8*)&Al[rA0 * 192 + pa0 * 8];
        #pragma unroll
        for (int ct = 0; ct < 4; ++ct) {
          const int rB = ct * 16 + m15;
          int pb = l + (rB % 24); if (pb >= 24) pb -= 24;
          bf16x8 b = *(const bf16x8*)&Bl[rB * 192 + pb * 8];
          acc[nt][ct] = __builtin_amdgcn_mfma_f32_16x16x32_bf16(a0, b, acc[nt][ct], 0, 0, 0);
        }
      }
    }
  }
  #pragma unroll
  for (int nt = 0; nt < 3; ++nt)
    #pragma unroll
    for (int ct = 0; ct < 4; ++ct)
      #pragma unroll
      for (int i = 0; i < 4; ++i) {
        long row = mBase + wv * 16 + quad * 4 + i;
        int col = nt * 64 + ct * 16 + m15;
        float v = acc[nt][ct][i] + bias[col] + addin[row * 192 + col];
        outp[row * 192 + col] = v;
      }
}

// ============ window attention: MFMA version, one wave per window-head ======
__global__ __launch_bounds__(256, 3) void attn_kernel(
    const float* __restrict__ rpe, __hip_bfloat16* __restrict__ qkv)
{
  __shared__ __align__(16) char smem[51968];
  const int tid = threadIdx.x;
  const int lane = tid & 63;
  const int wv = tid >> 6;
  const int quad = lane >> 4;
  const int m15 = lane & 15;
  const int wh = blockIdx.x * 4 + wv;
  const int h = wh & 7;
  const int win = wh >> 3;
  const int b = win >> 8;
  const int wl = win & 255;
  const int whi = wl >> 4;
  const int wwi = wl & 15;
  ushort* qkv_u = (ushort*)qkv;
  char* Vb = smem + wv * 4096;                       // V: [64 j][32 d] bf16
  char* Pb = smem + 16384 + wv * 8192;               // P: [64 r][64 j] bf16
  float* biasW = (float*)(smem + 49152 + wv * 704);  // 169 f32

  const long rowbase = (long)b * 12544 + (long)(whi * 7) * 112 + wwi * 7;

  // ---- stage V rows (swizzled) ; zero pad rows 49..63 (K-dim safety) ----
  {
    int j = lane;
    int f = ((j >> 3) & 3) << 5;
    if (j < 49) {
      int py = j / 7, px = j - py * 7;
      long row = rowbase + py * 112 + px;
      const ushort* src = qkv_u + row * 576 + 384 + h * 24;
      #pragma unroll
      for (int c = 0; c < 3; ++c) {
        u16x8 val = *(const u16x8*)(src + c * 8);
        *(u16x8*)(Vb + ((j * 64 + c * 16) ^ f)) = val;
      }
    } else {
      u16x8 z = {};
      #pragma unroll
      for (int c = 0; c < 4; ++c)
        *(u16x8*)(Vb + ((j * 64 + c * 16) ^ f)) = z;
    }
  }
  for (int r = lane; r < 169; r += 64) biasW[r] = rpe[r * 8 + h];

  // ---- relative-position index components ----
  int bi[4];
  #pragma unroll
  for (int rt = 0; rt < 4; ++rt) {
    int r = rt * 16 + m15; if (r > 48) r = 48;
    bi[rt] = (r / 7) * 13 + (r % 7) + 84;
  }
  int bj4[4][4];
  #pragma unroll
  for (int jt = 0; jt < 4; ++jt)
    #pragma unroll
    for (int i = 0; i < 4; ++i) {
      int j = jt * 16 + quad * 4 + i; if (j > 48) j = 48;
      bj4[jt][i] = (j / 7) * 13 + (j % 7);
    }

  // ---- S^T accumulators, bias as C-in ----
  f32x4 sacc[4][4];  // [jt][rt]
  #pragma unroll
  for (int jt = 0; jt < 4; ++jt)
    #pragma unroll
    for (int rt = 0; rt < 4; ++rt)
      #pragma unroll
      for (int i = 0; i < 4; ++i)
        sacc[jt][rt][i] = biasW[bi[rt] - bj4[jt][i]];

  // ---- K / Q fragments straight from global ----
  bf16x8 kf[4], qf[4];
  const bf16x8 zf = {};
  #pragma unroll
  for (int jt = 0; jt < 4; ++jt) {
    int t = jt * 16 + m15; if (t > 48) t = 48;
    long row = rowbase + (t / 7) * 112 + (t % 7);
    kf[jt] = *(const bf16x8*)(qkv_u + row * 576 + 192 + h * 24 + quad * 8);
    if (quad == 3) kf[jt] = zf;   // zero d=24..31 pad (one side zero -> ok)
  }
  #pragma unroll
  for (int rt = 0; rt < 4; ++rt) {
    int t = rt * 16 + m15; if (t > 48) t = 48;
    long row = rowbase + (t / 7) * 112 + (t % 7);
    qf[rt] = *(const bf16x8*)(qkv_u + row * 576 + h * 24 + quad * 8);
  }
  #pragma unroll
  for (int jt = 0; jt < 4; ++jt)
    #pragma unroll
    for (int rt = 0; rt < 4; ++rt)
      sacc[jt][rt] = __builtin_amdgcn_mfma_f32_16x16x32_bf16(
          kf[jt], qf[rt], sacc[jt][rt], 0, 0, 0);

  // ---- mask j >= 49 (jt=3: j = 48 + quad*4 + i) ----
  #pragma unroll
  for (int rt = 0; rt < 4; ++rt) {
    if (quad != 0) sacc[3][rt][0] = -1e30f;
    sacc[3][rt][1] = -1e30f;
    sacc[3][rt][2] = -1e30f;
    sacc[3][rt][3] = -1e30f;
  }

  // ---- softmax over j per r-column (unnormalized; inv kept per rt) ----
  float inv[4];
  #pragma unroll
  for (int rt = 0; rt < 4; ++rt) {
    float mx = sacc[0][rt][0];
    #pragma unroll
    for (int jt = 0; jt < 4; ++jt)
      #pragma unroll
      for (int i = 0; i < 4; ++i)
        mx = fmaxf(mx, sacc[jt][rt][i]);
    mx = fmaxf(mx, __shfl_xor(mx, 16, 64));
    mx = fmaxf(mx, __shfl_xor(mx, 32, 64));
    float sum = 0.f;
    #pragma unroll
    for (int jt = 0; jt < 4; ++jt)
      #pragma unroll
      for (int i = 0; i < 4; ++i) {
        float p = __expf(sacc[jt][rt][i] - mx);
        sacc[jt][rt][i] = p;
        sum += p;
      }
    sum += __shfl_xor(sum, 16, 64);
    sum += __shfl_xor(sum, 32, 64);
    inv[rt] = 1.f / sum;
  }

  // ---- P -> bf16 -> swizzled LDS ([64 r][64 j], byte ^= (m15&7)<<4) ----
  const int swzP = (m15 & 7) << 4;
  #pragma unroll
  for (int rt = 0; rt < 4; ++rt)
    #pragma unroll
    for (int jt = 0; jt < 4; ++jt)
      #pragma unroll
      for (int u = 0; u < 2; ++u) {
        unsigned pk;
        asm("v_cvt_pk_bf16_f32 %0, %1, %2"
            : "=v"(pk)
            : "v"(sacc[jt][rt][2 * u]), "v"(sacc[jt][rt][2 * u + 1]));
        int j0 = jt * 16 + quad * 4 + 2 * u;
        int lin = (rt * 16 + m15) * 128 + j0 * 2;
        *(unsigned*)(Pb + (lin ^ swzP)) = pk;
      }

  // ---- O = P.V ----
  f32x4 oacc[4][2];
  #pragma unroll
  for (int mt = 0; mt < 4; ++mt)
    #pragma unroll
    for (int nt = 0; nt < 2; ++nt) oacc[mt][nt] = (f32x4){0.f, 0.f, 0.f, 0.f};

  #pragma unroll
  for (int kt = 0; kt < 2; ++kt) {
    bf16x8 pf[4];
    #pragma unroll
    for (int mt = 0; mt < 4; ++mt) {
      int lin = (mt * 16 + m15) * 128 + kt * 64 + quad * 16;
      pf[mt] = *(const bf16x8*)(Pb + (lin ^ swzP));
    }
    bf16x8 vf[2];
    #pragma unroll
    for (int nt = 0; nt < 2; ++nt) {
      u32x4 w;
      #pragma unroll
      for (int e2 = 0; e2 < 4; ++e2) {
        int j_lo = kt * 32 + quad * 8 + 2 * e2;
        int lin_lo = j_lo * 64 + (nt * 16 + m15) * 2;
        int lin_hi = lin_lo + 64;
        unsigned lo = *(const ushort*)(Vb + (lin_lo ^ (quad << 5)));
        unsigned hi = *(const ushort*)(Vb + (lin_hi ^ (quad << 5)));
        w[e2] = lo | (hi << 16);
      }
      vf[nt] = __builtin_bit_cast(bf16x8, w);
    }
    #pragma unroll
    for (int mt = 0; mt < 4; ++mt)
      #pragma unroll
      for (int nt = 0; nt < 2; ++nt)
        oacc[mt][nt] = __builtin_amdgcn_mfma_f32_16x16x32_bf16(
            pf[mt], vf[nt], oacc[mt][nt], 0, 0, 0);
  }

  // ---- normalize (redistribute inv via bpermute) + store ----
  #pragma unroll
  for (int mt = 0; mt < 4; ++mt)
    #pragma unroll
    for (int i = 0; i < 4; ++i) {
      float iv = __shfl(inv[mt], quad * 4 + i, 64);
      int r = mt * 16 + quad * 4 + i;
      if (r < 49) {
        long row = rowbase + (r / 7) * 112 + (r % 7);
        ushort* dst = qkv_u + row * 576 + h * 24;
        dst[m15] = f2bfu(oacc[mt][0][i] * iv);
        if (m15 < 8) dst[16 + m15] = f2bfu(oacc[mt][1][i] * iv);
      }
    }
}

// -------- depthwise 3x3 conv + bias + tanh-GELU, minimal-state window -------
// R7 deep ring spilled to scratch (WRITE 114 MB vs 75 ideal) and regressed.
// Reverted to the R5-proven 4-slot named window (WRITE was exactly ideal =
// no spills), kept R6's fast GELU, and gated the tail prefetch (hh<14) so
// the 2 rows past the segment are never fetched.  1 row/iter, 16 iters.
__global__ __launch_bounds__(384, 8) void dwconv_gelu_kernel(
    const ushort* __restrict__ y1, const float* __restrict__ w,
    const float* __restrict__ bias, ushort* __restrict__ y2)
{
  const int c = threadIdx.x * 2;       // channel pair
  const int w0 = blockIdx.y * 2;       // output cols w0, w0+1
  const int b = blockIdx.z;
  const int h0 = blockIdx.x * 16;

  f32x2 wt[9];
  #pragma unroll
  for (int k = 0; k < 9; ++k)
    wt[k] = (f32x2){w[(c + 0) * 9 + k], w[(c + 1) * 9 + k]};
  const f32x2 bs = (f32x2){bias[c], bias[c + 1]};

  const bool okL = (w0 > 0), okR = (w0 + 2 < 112);

  uint rA[4], rB[4], rC[4], rD[4];   // rows h-1,h,h+1,h+2; cols w0-1..w0+2

  auto loadrow = [&](int h, uint dst[4]) {
    if (h < 0 || h >= 112) {
      dst[0] = 0u; dst[1] = 0u; dst[2] = 0u; dst[3] = 0u;
      return;
    }
    const ushort* p = y1 + (((size_t)(b * 112 + h)) * 112 + w0) * HID + c;
    dst[0] = okL ? *(const uint*)(p - HID) : 0u;
    dst[1] = *(const uint*)(p);
    dst[2] = *(const uint*)(p + HID);
    dst[3] = okR ? *(const uint*)(p + 2 * HID) : 0u;
  };

  auto accum = [&](const uint r[4], int dy, f32x2& a0, f32x2& a1) {
    f32x2 col[4];
    #pragma unroll
    for (int x = 0; x < 4; ++x)
      col[x] = (f32x2){__uint_as_float(r[x] << 16),
                       __uint_as_float(r[x] & 0xffff0000u)};
    #pragma unroll
    for (int dx = 0; dx < 3; ++dx) {
      a0 += wt[dy * 3 + dx] * col[dx];
      a1 += wt[dy * 3 + dx] * col[dx + 1];
    }
  };

  loadrow(h0 - 1, rA);
  loadrow(h0,     rB);
  loadrow(h0 + 1, rC);
  loadrow(h0 + 2, rD);

  #pragma unroll 4
  for (int hh = 0; hh < 16; ++hh) {
    const int h = h0 + hh;
    f32x2 a0 = bs, a1 = bs;
    accum(rA, 0, a0, a1);
    accum(rB, 1, a0, a1);
    accum(rC, 2, a0, a1);

    ushort* outp = y2 + (((size_t)(b * 112 + h)) * 112 + w0) * HID + c;
    unsigned q0, q1;
    {
      float g0 = fgelu(a0[0]), g1 = fgelu(a0[1]);
      float g2 = fgelu(a1[0]), g3 = fgelu(a1[1]);
      asm("v_cvt_pk_bf16_f32 %0, %1, %2" : "=v"(q0) : "v"(g0), "v"(g1));
      asm("v_cvt_pk_bf16_f32 %0, %1, %2" : "=v"(q1) : "v"(g2), "v"(g3));
    }
    *(uint*)(outp) = q0;
    *(uint*)(outp + HID) = q1;

    // rotate window, prefetch row h+3 (consumed 2 iterations later);
    // gate so rows past h0+16 are never fetched (R6/R7 wasted 2 rows)
    #pragma unroll
    for (int x = 0; x < 4; ++x) { rA[x] = rB[x]; rB[x] = rC[x]; rC[x] = rD[x]; }
    if (hh < 14) loadrow(h + 3, rD);
  }
}

// ---------------------------------------------------------------------------
extern "C" void kernel_launch(void* const* d_in, const int* in_sizes, int n_in,
                              void* d_out, int out_size, void* d_ws, size_t ws_size,
                              hipStream_t stream) {
  const float* x      = (const float*)d_in[0];
  const float* n1g    = (const float*)d_in[1];
  const float* n1b    = (const float*)d_in[2];
  const float* q_w    = (const float*)d_in[3];
  const float* q_b    = (const float*)d_in[4];
  const float* kv_w   = (const float*)d_in[5];
  const float* kv_b   = (const float*)d_in[6];
  const float* rpe    = (const float*)d_in[7];
  const float* proj_w = (const float*)d_in[8];
  const float* proj_b = (const float*)d_in[9];
  const float* n2g    = (const float*)d_in[10];
  const float* n2b    = (const float*)d_in[11];
  const float* fc1_w  = (const float*)d_in[12];
  const float* fc1_b  = (const float*)d_in[13];
  const float* dw_w   = (const float*)d_in[14];
  const float* dw_b   = (const float*)d_in[15];
  const float* fc2_w  = (const float*)d_in[16];
  const float* fc2_b  = (const float*)d_in[17];
  float* out = (float*)d_out;

  // ---- weights at front of ws (~0.9 MB) ----
  char* ws = (char*)d_ws;
  __hip_bfloat16* wcat  = (__hip_bfloat16*)(ws);               // 576*192 bf16
  __hip_bfloat16* projw = (__hip_bfloat16*)(ws + 221184);      // 192*192
  __hip_bfloat16* fc1w  = (__hip_bfloat16*)(ws + 294912);      // 768*192
  __hip_bfloat16* fc2w  = (__hip_bfloat16*)(ws + 589824);      // 192*768
  float* bcat           = (float*)(ws + 884736);               // 576 f32
  const size_t WOFF = 1u << 20;                                // 1 MB

  // ---- pick images-per-chunk CB so the activation buffers fit ws_size ----
  int CB = 8;
  while (CB > 1 && WOFF + (size_t)CB * 12544 * 3456 > ws_size) CB >>= 1;
  const size_t Mc = (size_t)CB * 12544;
  char* Abuf = ws + WOFF;                        // xn (bf16 Mc x 192)
  char* Bbuf = Abuf + Mc * 384;                  // qkv (Mc x 576) / y2 (Mc x 768)
  char* Cbuf = Bbuf + Mc * 1536;                 // y1 (bf16 Mc x 768)
  __hip_bfloat16* xn  = (__hip_bfloat16*)Abuf;
  __hip_bfloat16* qkv = (__hip_bfloat16*)Bbuf;
  __hip_bfloat16* y2  = (__hip_bfloat16*)Bbuf;
  __hip_bfloat16* y1  = (__hip_bfloat16*)Cbuf;

  prep_kernel<<<576, 256, 0, stream>>>(q_w, q_b, kv_w, kv_b, proj_w, fc1_w,
                                       fc2_w, wcat, bcat, projw, fc1w, fc2w);

  const int nChunks = 8 / CB;
  const int mt = CB * 98;
  for (int cchunk = 0; cchunk < nChunks; ++cchunk) {
    const size_t toff = (size_t)cchunk * Mc;
    const float* xc = x + toff * C_DIM;
    float* oc = out + toff * C_DIM;

    gemmA_lnin_kernel<<<dim3(1, mt), 512, 0, stream>>>(
        xc, n1g, n1b, (const ushort*)wcat, bcat, qkv, 576);
    attn_kernel<<<CB * 512, 256, 0, stream>>>(rpe, qkv);
    gemmA_ln_kernel<<<dim3(1, mt), 512, 0, stream>>>(
        (const ushort*)qkv, 576, (const ushort*)projw, proj_b, xc, oc,
        n2g, n2b, xn);
    gemmA_kernel<0><<<dim3(1, mt), 512, 0, stream>>>(
        (const ushort*)xn, 192, (const ushort*)fc1w, fc1_b, nullptr, y1, 768);
    dwconv_gelu_kernel<<<dim3(7, 56, CB), 384, 0, stream>>>(
        (const ushort*)y1, dw_w, dw_b, (ushort*)y2);
    gemmB_kernel<<<dim3(1, mt), 512, 0, stream>>>(
        (const ushort*)y2, (const ushort*)fc2w, fc2_b, oc, oc);
  }
}